// Round 10
// baseline (151.356 us; speedup 1.0000x reference)
//
#include <hip/hip_runtime.h>
#include <hip/hip_bf16.h>
#include <hip/hip_fp16.h>
#include <math.h>

#define NUM_H 8
#define DK    64
#define DM    512
#define SEQ   2048
#define NB    2
#define MROWS (NB*SEQ)   // 4096
#define NZ    4          // attn split-K factor

typedef unsigned short u16;
typedef unsigned int   u32;
typedef __attribute__((ext_vector_type(8)))  __bf16 bf16x8;
typedef __attribute__((ext_vector_type(4)))  float  f32x4;
typedef __attribute__((ext_vector_type(16))) float  f32x16;

// Native RNE cast (compiler emits v_cvt_pk_bf16_f32 for pairs).
__device__ __forceinline__ u16 f2bf(float v) {
    union { __bf16 h; u16 u; } x; x.h = (__bf16)v; return x.u;
}
__device__ __forceinline__ u16 f2h(float v) {
    union { _Float16 h; u16 u; } x; x.h = (_Float16)v; return x.u;
}
__device__ __forceinline__ float h2f(u16 u) {
    union { u16 u; _Float16 h; } x; x.u = u; return (float)x.h;
}
__device__ __forceinline__ bf16x8 ld_bf8(const u16* p) {
    union { uint4 u; bf16x8 v; } t;
    t.u = *(const uint4*)p;
    return t.v;
}
__device__ __forceinline__ uint4 pack8bf(const float* f) {
    uint4 o;
    o.x = (u32)f2bf(f[0]) | ((u32)f2bf(f[1]) << 16);
    o.y = (u32)f2bf(f[2]) | ((u32)f2bf(f[3]) << 16);
    o.z = (u32)f2bf(f[4]) | ((u32)f2bf(f[5]) << 16);
    o.w = (u32)f2bf(f[6]) | ((u32)f2bf(f[7]) << 16);
    return o;
}
__device__ __forceinline__ uint4 pack2f4(float4 a, float4 b) {
    float f[8] = {a.x, a.y, a.z, a.w, b.x, b.y, b.z, b.w};
    return pack8bf(f);
}
// exp2 that maps straight to v_exp_f32 (no hidden *log2e mul).
__device__ __forceinline__ float fexp2(float x) {
#if defined(__has_builtin) && __has_builtin(__builtin_amdgcn_exp2f)
    return __builtin_amdgcn_exp2f(x);
#else
    return exp2f(x);
#endif
}
__device__ __forceinline__ u32 pk2(float lo, float hi) {
    return (u32)f2bf(lo) | ((u32)f2bf(hi) << 16);
}
__device__ __forceinline__ bf16x8 frag4(u32 w0, u32 w1, u32 w2, u32 w3) {
    union { u32 u[4]; bf16x8 v; } t;
    t.u[0] = w0; t.u[1] = w1; t.u[2] = w2; t.u[3] = w3;
    return t.v;
}
__device__ __forceinline__ f32x16 mfma32(bf16x8 a, bf16x8 b, f32x16 c) {
    return __builtin_amdgcn_mfma_f32_32x32x16_bf16(a, b, c, 0, 0, 0);
}

// Convert Wq,Wk,Wv,Wo (fp32 512x512) -> bf16 into Wscr. grid (128,4) x 256.
__global__ __launch_bounds__(256) void convW(
    const float* __restrict__ Wq, const float* __restrict__ Wk,
    const float* __restrict__ Wv, const float* __restrict__ Wo,
    u16* __restrict__ Wscr)
{
    const int z = blockIdx.y;
    const float* src = (z == 0) ? Wq : (z == 1) ? Wk : (z == 2) ? Wv : Wo;
    u16* dst = Wscr + (size_t)z * 262144;
    int i = (blockIdx.x * 256 + threadIdx.x) * 8;
    float4 a = *(const float4*)(src + i);
    float4 b = *(const float4*)(src + i + 4);
    float f[8] = {a.x, a.y, a.z, a.w, b.x, b.y, b.z, b.w};
    *(uint4*)&dst[i] = pack8bf(f);
}

// ---------------- MFMA GEMM core: OUT = X @ W^T + bias (W bf16) ----------------
// r15/r17-proven shape: BM=BN=BK=64, 256 thr / 4 waves (2x2, 32x32 out each),
// LDS stride 72 u16, single-buffer 2-barrier K-loop. r21: combine de-fused.
// r22: T14 register prefetch (the r14-proven attn pattern, isolated from the
// r16 bundle whose convAll masked its gain): prologue-load tile 0 to regs;
// loop = ds_write(staged) -> barrier -> issue kt+64 loads -> MFMA -> barrier.
// Global-load latency (~500cy x 8 iters) now hides under MFMA instead of
// stalling the staging phase. NOT r19's LDS dbuf (LDS stays single-buffered).
#define MODE_QK 0
#define MODE_VT 1
#define MODE_FIN 2

template<int MODE, bool INBF>
__device__ __forceinline__ void gemm_core(
    const void* __restrict__ Xv, const u16* __restrict__ Wb,
    const float* __restrict__ bias, void* __restrict__ outv,
    u16* As, u16* Bs, int row0, int col0)
{
    const int tid = threadIdx.x;
    const int lane = tid & 63, w = tid >> 6;
    const int ln15 = lane & 15, quad = lane >> 4;
    const int wm = (w >> 1) * 32, wn = (w & 1) * 32;
    const int sr = tid >> 3;          // staging row 0..31 (+32 for g=1)
    const int sc = (tid & 7) * 8;     // staging col

    f32x4 acc[2][2];
#pragma unroll
    for (int mt = 0; mt < 2; ++mt)
#pragma unroll
        for (int nt = 0; nt < 2; ++nt) acc[mt][nt] = (f32x4){0.f, 0.f, 0.f, 0.f};

    // staging source pointers (advance by kt)
    const float* af0 = (const float*)Xv + (size_t)(row0 + sr) * DM + sc;
    const float* af1 = (const float*)Xv + (size_t)(row0 + 32 + sr) * DM + sc;
    const u16*   ab0 = (const u16*)Xv + (size_t)(row0 + sr) * DM + sc;
    const u16*   ab1 = (const u16*)Xv + (size_t)(row0 + 32 + sr) * DM + sc;
    const u16*   bb0 = Wb + (size_t)(col0 + sr) * DM + sc;
    const u16*   bb1 = Wb + (size_t)(col0 + 32 + sr) * DM + sc;

    // T14 prefetch registers
    float4 pa0a, pa0b, pa1a, pa1b;    // fp32 A path
    uint4  qa0, qa1;                  // bf16 A path (INBF)
    uint4  pb0, pb1;

    // prologue: tile 0
    if (INBF) {
        qa0 = *(const uint4*)(ab0);
        qa1 = *(const uint4*)(ab1);
    } else {
        pa0a = *(const float4*)(af0);     pa0b = *(const float4*)(af0 + 4);
        pa1a = *(const float4*)(af1);     pa1b = *(const float4*)(af1 + 4);
    }
    pb0 = *(const uint4*)(bb0);
    pb1 = *(const uint4*)(bb1);

    for (int kt = 0; kt < DM; kt += 64) {
        // write staged regs to LDS (prev compute done at loop-end barrier)
        if (INBF) {
            *(uint4*)&As[sr * 72 + sc]        = qa0;
            *(uint4*)&As[(sr + 32) * 72 + sc] = qa1;
        } else {
            *(uint4*)&As[sr * 72 + sc]        = pack2f4(pa0a, pa0b);
            *(uint4*)&As[(sr + 32) * 72 + sc] = pack2f4(pa1a, pa1b);
        }
        *(uint4*)&Bs[sr * 72 + sc]        = pb0;
        *(uint4*)&Bs[(sr + 32) * 72 + sc] = pb1;
        __syncthreads();

        // issue next tile's loads — they complete under the MFMAs
        if (kt + 64 < DM) {
            if (INBF) {
                qa0 = *(const uint4*)(ab0 + kt + 64);
                qa1 = *(const uint4*)(ab1 + kt + 64);
            } else {
                pa0a = *(const float4*)(af0 + kt + 64);
                pa0b = *(const float4*)(af0 + kt + 64 + 4);
                pa1a = *(const float4*)(af1 + kt + 64);
                pa1b = *(const float4*)(af1 + kt + 64 + 4);
            }
            pb0 = *(const uint4*)(bb0 + kt + 64);
            pb1 = *(const uint4*)(bb1 + kt + 64);
        }

#pragma unroll
        for (int ks = 0; ks < 2; ++ks) {
            bf16x8 af[2], bfr[2];
#pragma unroll
            for (int mt = 0; mt < 2; ++mt)
                af[mt] = ld_bf8(&As[(wm + mt * 16 + ln15) * 72 + ks * 32 + quad * 8]);
#pragma unroll
            for (int nt = 0; nt < 2; ++nt)
                bfr[nt] = ld_bf8(&Bs[(wn + nt * 16 + ln15) * 72 + ks * 32 + quad * 8]);
#pragma unroll
            for (int mt = 0; mt < 2; ++mt)
#pragma unroll
                for (int nt = 0; nt < 2; ++nt)
                    acc[mt][nt] = __builtin_amdgcn_mfma_f32_16x16x32_bf16(
                        af[mt], bfr[nt], acc[mt][nt], 0, 0, 0);
        }
        __syncthreads();
    }

    float bc[2];
#pragma unroll
    for (int nt = 0; nt < 2; ++nt) bc[nt] = bias[col0 + wn + nt * 16 + ln15];
    const int h = col0 >> 6;   // BN=64 == one head

    if (MODE == MODE_FIN) {
        float* outF = (float*)outv;
#pragma unroll
        for (int mt = 0; mt < 2; ++mt)
#pragma unroll
            for (int r = 0; r < 4; ++r) {
                int m = row0 + wm + mt * 16 + quad * 4 + r;
#pragma unroll
                for (int nt = 0; nt < 2; ++nt)
                    outF[(size_t)m * DM + col0 + wn + nt * 16 + ln15] = acc[mt][nt][r] + bc[nt];
            }
    } else if (MODE == MODE_QK) {
        u16* outB = (u16*)outv;
#pragma unroll
        for (int mt = 0; mt < 2; ++mt)
#pragma unroll
            for (int r = 0; r < 4; ++r) {
                int m = row0 + wm + mt * 16 + quad * 4 + r;
                int b = m >> 11, s2 = m & (SEQ - 1);
#pragma unroll
                for (int nt = 0; nt < 2; ++nt) {
                    int dk = wn + nt * 16 + ln15;
                    outB[((size_t)((b * NUM_H + h) * SEQ + s2)) * DK + dk] =
                        f2bf(acc[mt][nt][r] + bc[nt]);
                }
            }
    } else {   // MODE_VT: out [b][h][dk][s]; LDS transpose (reuse As, 64x72)
        u16* outB = (u16*)outv;
        __syncthreads();   // all frag reads done before As reuse
#pragma unroll
        for (int mt = 0; mt < 2; ++mt)
#pragma unroll
            for (int nt = 0; nt < 2; ++nt) {
                int dk = wn + nt * 16 + ln15;
#pragma unroll
                for (int r = 0; r < 4; ++r) {
                    int sl = wm + mt * 16 + quad * 4 + r;
                    As[dk * 72 + sl] = f2bf(acc[mt][nt][r] + bc[nt]);
                }
            }
        __syncthreads();
        int dk = tid >> 2, ch = (tid & 3) * 16;
        int b = row0 >> 11, s0 = row0 & (SEQ - 1);
        size_t base = ((size_t)((b * NUM_H + h) * DK + dk)) * SEQ + s0 + ch;
        *(uint4*)&outB[base]     = *(const uint4*)&As[dk * 72 + ch];
        *(uint4*)&outB[base + 8] = *(const uint4*)&As[dk * 72 + ch + 8];
    }
}

// Fused QKV: grid (64, 8, 3). Inputs fp32 (bf16-packed during staging).
__global__ __launch_bounds__(256) void qkv_mfma(
    const float* __restrict__ xq, const float* __restrict__ xk, const float* __restrict__ xv,
    const u16* __restrict__ Wscr,
    const float* __restrict__ b0, const float* __restrict__ b1, const float* __restrict__ b2,
    u16* __restrict__ oQ, u16* __restrict__ oK, u16* __restrict__ oVt)
{
    __shared__ u16 As[64 * 72];
    __shared__ u16 Bs[64 * 72];
    const int row0 = blockIdx.x * 64, col0 = blockIdx.y * 64;
    const int z = blockIdx.z;
    const u16* W = Wscr + (size_t)z * 262144;
    if (z == 2)
        gemm_core<MODE_VT, false>(xv, W, b2, oVt, As, Bs, row0, col0);
    else if (z == 0)
        gemm_core<MODE_QK, false>(xq, W, b0, oQ, As, Bs, row0, col0);
    else
        gemm_core<MODE_QK, false>(xk, W, b1, oK, As, Bs, row0, col0);
}

// Final projection: A is bf16 C from the combine kernel (INBF path).
__global__ __launch_bounds__(256) void final_mfma(
    const u16* __restrict__ X, const u16* __restrict__ Wbf,
    const float* __restrict__ bias, float* __restrict__ out)
{
    __shared__ u16 As[64 * 72];
    __shared__ u16 Bs[64 * 72];
    gemm_core<MODE_FIN, true>(X, Wbf, bias, out, As, Bs,
                              blockIdx.x * 64, blockIdx.y * 64);
}

// Combine: C = 64*(sum_z O_z)/(sum_z l_z) -> bf16 into Qb region (Q is dead
// after attn). Memory-bound streaming kernel: grid 1024 x 256, 4 blocks/CU.
__global__ __launch_bounds__(256) void combine(
    const u16* __restrict__ Pd, const float* __restrict__ Cl, u16* __restrict__ C)
{
    int idx = (blockIdx.x * 256 + threadIdx.x) * 8;
    int row = idx >> 9, col = idx & 511;
    int b = row >> 11, s = row & (SEQ - 1), h = col >> 6;
    int bh = b * NUM_H + h;
    float lsum = Cl[bh * SEQ + s] + Cl[32768 + bh * SEQ + s]
               + Cl[65536 + bh * SEQ + s] + Cl[98304 + bh * SEQ + s];
    float sc = 64.f / lsum;
    union { uint4 u; __half2 h2[4]; } u0, u1, u2, u3;
    u0.u = *(const uint4*)&Pd[idx];
    u1.u = *(const uint4*)&Pd[2097152 + idx];
    u2.u = *(const uint4*)&Pd[2 * 2097152 + idx];
    u3.u = *(const uint4*)&Pd[3 * 2097152 + idx];
    float f[8];
#pragma unroll
    for (int j = 0; j < 4; ++j) {
        __half2 s2 = __hadd2(__hadd2(u0.h2[j], u1.h2[j]),
                             __hadd2(u2.h2[j], u3.h2[j]));
        float2 fl = __half22float2(s2);
        f[2 * j]     = fl.x * sc;
        f[2 * j + 1] = fl.y * sc;
    }
    *(uint4*)&C[idx] = pack8bf(f);
}

// ---------------- MFMA flash attention, split-K4, diagonal mask ----------------
// r20 structure (kept): 32x32x16 MFMAs, each wave owns 32 q rows,
// S^T = mfma32(K,Q) so lane holds ONE q (lane&31); l-sum is a scalar
// register; P->PV A-frag via 2 v_permlane32_swap_b32 per 16-k block;
// PV 8 mfma32/tile with b128 V reads. Single-buffer 2-barrier loop + T14
// reg prefetch (r19's 1-barrier dbuf regressed).
#define LSTR 72
// exp(z*0.125 - 4) == exp2(z*0.125*log2e - 4*log2e)
#define SCL2  0.18033688f
#define BIA2 -5.7708020f
__global__ __launch_bounds__(256, 4) void attn_mfma(
    const u16* __restrict__ Qg, const u16* __restrict__ Kg,
    const u16* __restrict__ Vtg, u16* __restrict__ Pd, float* __restrict__ Cl)
{
    __shared__ u16 Klds[64 * LSTR];
    __shared__ u16 Vtlds[64 * LSTR];

    const int tid = threadIdx.x;
    const int lane = tid & 63;
    const int w = tid >> 6;
    const int col = lane & 31;          // q-col / key-row within 32-block
    const int hi  = lane >> 5;
    const int hi8 = hi * 8;
    const int bh = blockIdx.y;
    const int b = bh >> 3, h = bh & 7;
    const int qb = blockIdx.z * 128;    // 16 q-blocks of 128 rows
    const int z = blockIdx.x;           // NZ split-K slabs
    const int k0 = z * (SEQ / NZ), k1 = k0 + SEQ / NZ;

    const u16* Qp = Qg + (size_t)bh * SEQ * DK;
    const u16* Kp = Kg + (size_t)bh * SEQ * DK;
    const u16* Vp = Vtg + (size_t)bh * DK * SEQ;   // [d][s]

    // Q fragments (B-operand): col q = lane&31, dk = dkb*16 + hi8 + j
    const int myq = qb + w * 32 + col;
    bf16x8 qf[4];
#pragma unroll
    for (int dkb = 0; dkb < 4; ++dkb)
        qf[dkb] = ld_bf8(&Qp[(size_t)myq * DK + dkb * 16 + hi8]);

    // diagonal: q == kt + kb32*32 + crow0 + 4*hi, with kt==diag_kt and
    // kb32==(w&1) -> mask reg r where crow0(r) == vtarget.
    const int diag_kt = qb + (w >> 1) * 64;
    const int vtarget = col - 4 * hi;

    f32x16 O0 = {0.f, 0.f, 0.f, 0.f, 0.f, 0.f, 0.f, 0.f,
                 0.f, 0.f, 0.f, 0.f, 0.f, 0.f, 0.f, 0.f};
    f32x16 O1 = O0;
    float lsum = 0.f;

    const int sr = tid >> 3;
    const int scl = (tid & 7) * 8;
    const u16* kp0 = &Kp[(size_t)sr * DK + scl];
    const u16* kp1 = &Kp[(size_t)(sr + 32) * DK + scl];
    const u16* vp0 = &Vp[(size_t)sr * SEQ + scl];
    const u16* vp1 = &Vp[(size_t)(sr + 32) * SEQ + scl];

    // T14 prologue: first tile into regs
    uint4 kreg0 = *(const uint4*)&kp0[(size_t)k0 * DK];
    uint4 kreg1 = *(const uint4*)&kp1[(size_t)k0 * DK];
    uint4 vreg0 = *(const uint4*)&vp0[k0];
    uint4 vreg1 = *(const uint4*)&vp1[k0];

    for (int kt = k0; kt < k1; kt += 64) {
        // write staged regs to LDS (prev compute finished at loop-end barrier)
        *(uint4*)&Klds[sr * LSTR + scl]         = kreg0;
        *(uint4*)&Klds[(sr + 32) * LSTR + scl]  = kreg1;
        *(uint4*)&Vtlds[sr * LSTR + scl]        = vreg0;
        *(uint4*)&Vtlds[(sr + 32) * LSTR + scl] = vreg1;
        __syncthreads();

        // issue next tile's global loads — they complete under compute
        if (kt + 64 < k1) {
            kreg0 = *(const uint4*)&kp0[(size_t)(kt + 64) * DK];
            kreg1 = *(const uint4*)&kp1[(size_t)(kt + 64) * DK];
            vreg0 = *(const uint4*)&vp0[kt + 64];
            vreg1 = *(const uint4*)&vp1[kt + 64];
        }

        const bool diagt = (kt == diag_kt);
        __builtin_amdgcn_s_setprio(1);
#pragma unroll
        for (int kb32 = 0; kb32 < 2; ++kb32) {
            // QK^T: S^T block (32 keys x 32 q)
            f32x16 z16 = {0.f, 0.f, 0.f, 0.f, 0.f, 0.f, 0.f, 0.f,
                          0.f, 0.f, 0.f, 0.f, 0.f, 0.f, 0.f, 0.f};
#pragma unroll
            for (int dkb = 0; dkb < 4; ++dkb) {
                bf16x8 kf = ld_bf8(&Klds[(kb32 * 32 + col) * LSTR + dkb * 16 + hi8]);
                z16 = mfma32(kf, qf[dkb], z16);
            }
            const bool dm = diagt && (kb32 == (w & 1));
#pragma unroll
            for (int c = 0; c < 2; ++c) {       // two 16-k sub-blocks
                float e[8];
#pragma unroll
                for (int i = 0; i < 8; ++i) {
                    const int r = c * 8 + i;
                    float ee = fexp2(fmaf(z16[r], SCL2, BIA2));
                    const int crow0 = (r & 3) + 8 * (r >> 2);
                    if (dm && vtarget == crow0) ee = 0.f;
                    lsum += ee;
                    e[i] = ee;
                }
                u32 a0 = pk2(e[0], e[1]);
                u32 a1 = pk2(e[2], e[3]);
                u32 a2 = pk2(e[4], e[5]);
                u32 a3 = pk2(e[6], e[7]);
                asm("v_permlane32_swap_b32 %0, %1" : "+v"(a0), "+v"(a2));
                asm("v_permlane32_swap_b32 %0, %1" : "+v"(a1), "+v"(a3));
                bf16x8 paf = frag4(a0, a1, a2, a3);
                const int kb16 = kb32 * 2 + c;
                bf16x8 vf0 = ld_bf8(&Vtlds[col * LSTR + kb16 * 16 + hi8]);
                bf16x8 vf1 = ld_bf8(&Vtlds[(32 + col) * LSTR + kb16 * 16 + hi8]);
                O0 = mfma32(paf, vf0, O0);
                O1 = mfma32(paf, vf1, O1);
            }
        }
        __builtin_amdgcn_s_setprio(0);
        __syncthreads();
    }

    // l per q: lane holds q = col; partner lane^32 holds complementary k-set
    float lt = lsum + __shfl_xor(lsum, 32);
    if (lane < 32)
        Cl[(size_t)z * 32768 + bh * SEQ + qb + w * 32 + col] = lt;

    // write unnormalized O partial (fp16, scaled 1/64)
#pragma unroll
    for (int reg = 0; reg < 16; ++reg) {
        const int crow = (reg & 3) + 8 * (reg >> 2) + 4 * hi;
        const int sq = qb + w * 32 + crow;
        size_t base = (size_t)z * 2097152 + ((size_t)(b * SEQ + sq)) * DM + h * DK;
        Pd[base + col]      = f2h(O0[reg] * 0.015625f);
        Pd[base + 32 + col] = f2h(O1[reg] * 0.015625f);
    }
}

extern "C" void kernel_launch(void* const* d_in, const int* in_sizes, int n_in,
                              void* d_out, int out_size, void* d_ws, size_t ws_size,
                              hipStream_t stream) {
    const float* q  = (const float*)d_in[0];
    const float* k  = (const float*)d_in[1];
    const float* v  = (const float*)d_in[2];
    const float* Wq = (const float*)d_in[3];
    const float* bq = (const float*)d_in[4];
    const float* Wk = (const float*)d_in[5];
    const float* bk = (const float*)d_in[6];
    const float* Wv = (const float*)d_in[7];
    const float* bv = (const float*)d_in[8];
    const float* Wo = (const float*)d_in[9];
    const float* bo = (const float*)d_in[10];
    float* out = (float*)d_out;

    // ws layout (~30.5 MB of the 256 MB arena):
    //   Qb, Kb, Vtb   bf16 [4096][512]        4 MB each (Qb reused for C)
    //   Cl            fp32 [NZ][16][2048]     512 KB
    //   Wscr          bf16 Wq,Wk,Wv,Wo        2 MB
    //   Pd            fp16 [NZ][4096][512]    16 MB (attn O-partials)
    const size_t TSZ = (size_t)MROWS * DM;   // 2,097,152
    u16* Qb   = (u16*)d_ws;
    u16* Kb   = Qb + TSZ;
    u16* Vtb  = Qb + 2 * TSZ;
    float* Cl = (float*)(Qb + 3 * TSZ);      // NZ*32768 = 131072 floats
    u16* Wscr = (u16*)(Cl + 131072);         // 4*262144 u16
    u16* Pd   = Wscr + 4 * 262144;           // NZ*TSZ u16

    dim3 blk(256);
    hipLaunchKernelGGL(convW, dim3(128, 4), blk, 0, stream, Wq, Wk, Wv, Wo, Wscr);
    dim3 gq(MROWS / 64, DM / 64, 3);         // (64, 8, 3) = 1536 blocks, 6/CU
    hipLaunchKernelGGL(qkv_mfma, gq, blk, 0, stream,
                       q, k, v, Wscr, bq, bk, bv, Qb, Kb, Vtb);
    dim3 ga(NZ, NB * NUM_H, SEQ / 128);      // (4, 16, 16) = 1024 blocks, 4/CU
    hipLaunchKernelGGL(attn_mfma, ga, blk, 0, stream, Qb, Kb, Vtb, Pd, Cl);
    hipLaunchKernelGGL(combine, dim3(1024), blk, 0, stream, Pd, Cl, Qb);  // C -> Qb
    dim3 gf(MROWS / 64, DM / 64);            // (64, 8) = 512 blocks, 2/CU
    hipLaunchKernelGGL(final_mfma, gf, blk, 0, stream, Qb, Wscr + 3 * 262144, bo, out);
}

// Round 11
// 149.405 us; speedup vs baseline: 1.0131x; 1.0131x over previous
//
#include <hip/hip_runtime.h>
#include <hip/hip_bf16.h>
#include <hip/hip_fp16.h>
#include <math.h>

#define NUM_H 8
#define DK    64
#define DM    512
#define SEQ   2048
#define NB    2
#define MROWS (NB*SEQ)   // 4096
#define NZ    4          // attn split-K factor

typedef unsigned short u16;
typedef unsigned int   u32;
typedef __attribute__((ext_vector_type(8)))  __bf16 bf16x8;
typedef __attribute__((ext_vector_type(4)))  float  f32x4;
typedef __attribute__((ext_vector_type(16))) float  f32x16;

// Native RNE cast (compiler emits v_cvt_pk_bf16_f32 for pairs).
__device__ __forceinline__ u16 f2bf(float v) {
    union { __bf16 h; u16 u; } x; x.h = (__bf16)v; return x.u;
}
__device__ __forceinline__ u16 f2h(float v) {
    union { _Float16 h; u16 u; } x; x.h = (_Float16)v; return x.u;
}
__device__ __forceinline__ float h2f(u16 u) {
    union { u16 u; _Float16 h; } x; x.u = u; return (float)x.h;
}
__device__ __forceinline__ bf16x8 ld_bf8(const u16* p) {
    union { uint4 u; bf16x8 v; } t;
    t.u = *(const uint4*)p;
    return t.v;
}
__device__ __forceinline__ uint4 pack8bf(const float* f) {
    uint4 o;
    o.x = (u32)f2bf(f[0]) | ((u32)f2bf(f[1]) << 16);
    o.y = (u32)f2bf(f[2]) | ((u32)f2bf(f[3]) << 16);
    o.z = (u32)f2bf(f[4]) | ((u32)f2bf(f[5]) << 16);
    o.w = (u32)f2bf(f[6]) | ((u32)f2bf(f[7]) << 16);
    return o;
}
// exp2 that maps straight to v_exp_f32 (no hidden *log2e mul).
__device__ __forceinline__ float fexp2(float x) {
#if defined(__has_builtin) && __has_builtin(__builtin_amdgcn_exp2f)
    return __builtin_amdgcn_exp2f(x);
#else
    return exp2f(x);
#endif
}
__device__ __forceinline__ u32 pk2(float lo, float hi) {
    return (u32)f2bf(lo) | ((u32)f2bf(hi) << 16);
}
__device__ __forceinline__ bf16x8 frag4(u32 w0, u32 w1, u32 w2, u32 w3) {
    union { u32 u[4]; bf16x8 v; } t;
    t.u[0] = w0; t.u[1] = w1; t.u[2] = w2; t.u[3] = w3;
    return t.v;
}
__device__ __forceinline__ f32x16 mfma32(bf16x8 a, bf16x8 b, f32x16 c) {
    return __builtin_amdgcn_mfma_f32_32x32x16_bf16(a, b, c, 0, 0, 0);
}

// Convert Wq,Wk,Wv,Wo (fp32 512x512) -> bf16 into Wscr. grid (128,4) x 256.
__global__ __launch_bounds__(256) void convW(
    const float* __restrict__ Wq, const float* __restrict__ Wk,
    const float* __restrict__ Wv, const float* __restrict__ Wo,
    u16* __restrict__ Wscr)
{
    const int z = blockIdx.y;
    const float* src = (z == 0) ? Wq : (z == 1) ? Wk : (z == 2) ? Wv : Wo;
    u16* dst = Wscr + (size_t)z * 262144;
    int i = (blockIdx.x * 256 + threadIdx.x) * 8;
    float4 a = *(const float4*)(src + i);
    float4 b = *(const float4*)(src + i + 4);
    float f[8] = {a.x, a.y, a.z, a.w, b.x, b.y, b.z, b.w};
    *(uint4*)&dst[i] = pack8bf(f);
}

// ---------------- MFMA GEMM core: OUT = X @ W^T + bias (W bf16) ----------------
// r21-proven (r22's T14 prefetch REVERTED — 3rd failed attempt at source-level
// GEMM pipelining; these kernels are TLP-hidden, only occupancy matters):
// BM=BN=BK=64, 256 thr / 4 waves (2x2, 32x32 out each), LDS stride 72 u16,
// single-buffer 2-barrier K-loop.
#define MODE_QK 0
#define MODE_VT 1
#define MODE_FIN 2

template<int MODE, bool INBF>
__device__ __forceinline__ void gemm_core(
    const void* __restrict__ Xv, const u16* __restrict__ Wb,
    const float* __restrict__ bias, void* __restrict__ outv,
    u16* As, u16* Bs, int row0, int col0)
{
    const int tid = threadIdx.x;
    const int lane = tid & 63, w = tid >> 6;
    const int ln15 = lane & 15, quad = lane >> 4;
    const int wm = (w >> 1) * 32, wn = (w & 1) * 32;

    f32x4 acc[2][2];
#pragma unroll
    for (int mt = 0; mt < 2; ++mt)
#pragma unroll
        for (int nt = 0; nt < 2; ++nt) acc[mt][nt] = (f32x4){0.f, 0.f, 0.f, 0.f};

    for (int kt = 0; kt < DM; kt += 64) {
        __syncthreads();
        // stage A: 64x64
#pragma unroll
        for (int g = 0; g < 2; ++g) {
            int idx = g * 2048 + tid * 8;
            int r = idx >> 6, c = idx & 63;
            if (INBF) {
                *(uint4*)&As[r * 72 + c] =
                    *(const uint4*)((const u16*)Xv + (size_t)(row0 + r) * DM + kt + c);
            } else {
                const float* xp = (const float*)Xv + (size_t)(row0 + r) * DM + kt + c;
                float4 a = *(const float4*)xp;
                float4 b2 = *(const float4*)(xp + 4);
                float f[8] = {a.x, a.y, a.z, a.w, b2.x, b2.y, b2.z, b2.w};
                *(uint4*)&As[r * 72 + c] = pack8bf(f);
            }
        }
        // stage B: 64x64, W bf16 layout [n][k]
#pragma unroll
        for (int g = 0; g < 2; ++g) {
            int idx = g * 2048 + tid * 8;
            int r = idx >> 6, c = idx & 63;
            *(uint4*)&Bs[r * 72 + c] =
                *(const uint4*)(Wb + (size_t)(col0 + r) * DM + kt + c);
        }
        __syncthreads();

#pragma unroll
        for (int ks = 0; ks < 2; ++ks) {
            bf16x8 af[2], bfr[2];
#pragma unroll
            for (int mt = 0; mt < 2; ++mt)
                af[mt] = ld_bf8(&As[(wm + mt * 16 + ln15) * 72 + ks * 32 + quad * 8]);
#pragma unroll
            for (int nt = 0; nt < 2; ++nt)
                bfr[nt] = ld_bf8(&Bs[(wn + nt * 16 + ln15) * 72 + ks * 32 + quad * 8]);
#pragma unroll
            for (int mt = 0; mt < 2; ++mt)
#pragma unroll
                for (int nt = 0; nt < 2; ++nt)
                    acc[mt][nt] = __builtin_amdgcn_mfma_f32_16x16x32_bf16(
                        af[mt], bfr[nt], acc[mt][nt], 0, 0, 0);
        }
    }

    float bc[2];
#pragma unroll
    for (int nt = 0; nt < 2; ++nt) bc[nt] = bias[col0 + wn + nt * 16 + ln15];
    const int h = col0 >> 6;   // BN=64 == one head

    if (MODE == MODE_FIN) {
        float* outF = (float*)outv;
#pragma unroll
        for (int mt = 0; mt < 2; ++mt)
#pragma unroll
            for (int r = 0; r < 4; ++r) {
                int m = row0 + wm + mt * 16 + quad * 4 + r;
#pragma unroll
                for (int nt = 0; nt < 2; ++nt)
                    outF[(size_t)m * DM + col0 + wn + nt * 16 + ln15] = acc[mt][nt][r] + bc[nt];
            }
    } else if (MODE == MODE_QK) {
        u16* outB = (u16*)outv;
#pragma unroll
        for (int mt = 0; mt < 2; ++mt)
#pragma unroll
            for (int r = 0; r < 4; ++r) {
                int m = row0 + wm + mt * 16 + quad * 4 + r;
                int b = m >> 11, s2 = m & (SEQ - 1);
#pragma unroll
                for (int nt = 0; nt < 2; ++nt) {
                    int dk = wn + nt * 16 + ln15;
                    outB[((size_t)((b * NUM_H + h) * SEQ + s2)) * DK + dk] =
                        f2bf(acc[mt][nt][r] + bc[nt]);
                }
            }
    } else {   // MODE_VT: out [b][h][dk][s]; LDS transpose (reuse As, 64x72)
        u16* outB = (u16*)outv;
        __syncthreads();   // all frag reads done before As reuse
#pragma unroll
        for (int mt = 0; mt < 2; ++mt)
#pragma unroll
            for (int nt = 0; nt < 2; ++nt) {
                int dk = wn + nt * 16 + ln15;
#pragma unroll
                for (int r = 0; r < 4; ++r) {
                    int sl = wm + mt * 16 + quad * 4 + r;
                    As[dk * 72 + sl] = f2bf(acc[mt][nt][r] + bc[nt]);
                }
            }
        __syncthreads();
        int dk = tid >> 2, ch = (tid & 3) * 16;
        int b = row0 >> 11, s0 = row0 & (SEQ - 1);
        size_t base = ((size_t)((b * NUM_H + h) * DK + dk)) * SEQ + s0 + ch;
        *(uint4*)&outB[base]     = *(const uint4*)&As[dk * 72 + ch];
        *(uint4*)&outB[base + 8] = *(const uint4*)&As[dk * 72 + ch + 8];
    }
}

// Fused QKV: grid (64, 8, 3). Inputs fp32 (bf16-packed during staging).
__global__ __launch_bounds__(256) void qkv_mfma(
    const float* __restrict__ xq, const float* __restrict__ xk, const float* __restrict__ xv,
    const u16* __restrict__ Wscr,
    const float* __restrict__ b0, const float* __restrict__ b1, const float* __restrict__ b2,
    u16* __restrict__ oQ, u16* __restrict__ oK, u16* __restrict__ oVt)
{
    __shared__ u16 As[64 * 72];
    __shared__ u16 Bs[64 * 72];
    const int row0 = blockIdx.x * 64, col0 = blockIdx.y * 64;
    const int z = blockIdx.z;
    const u16* W = Wscr + (size_t)z * 262144;
    if (z == 2)
        gemm_core<MODE_VT, false>(xv, W, b2, oVt, As, Bs, row0, col0);
    else if (z == 0)
        gemm_core<MODE_QK, false>(xq, W, b0, oQ, As, Bs, row0, col0);
    else
        gemm_core<MODE_QK, false>(xk, W, b1, oK, As, Bs, row0, col0);
}

// Final projection, r23: BM=32 for occupancy — grid (128, 8) = 1024 blocks =
// 4/CU (was 2/CU at BM=64; this kernel is latency-bound, and the r17/r18
// evidence says occupancy is the only lever that moves these GEMMs).
// 4 waves each own a 16x32 out tile (wm in {0,16}, wn in {0,32}).
__global__ __launch_bounds__(256) void final_mfma(
    const u16* __restrict__ X, const u16* __restrict__ Wbf,
    const float* __restrict__ bias, float* __restrict__ out)
{
    __shared__ u16 As[32 * 72];
    __shared__ u16 Bs[64 * 72];
    const int row0 = blockIdx.x * 32, col0 = blockIdx.y * 64;
    const int tid = threadIdx.x;
    const int lane = tid & 63, w = tid >> 6;
    const int ln15 = lane & 15, quad = lane >> 4;
    const int wm = (w >> 1) * 16, wn = (w & 1) * 32;
    const int sr = tid >> 3, sc = (tid & 7) * 8;

    f32x4 acc[2];
    acc[0] = (f32x4){0.f, 0.f, 0.f, 0.f};
    acc[1] = (f32x4){0.f, 0.f, 0.f, 0.f};

    for (int kt = 0; kt < DM; kt += 64) {
        __syncthreads();
        // stage A: 32x64 bf16 (one uint4 per thread)
        *(uint4*)&As[sr * 72 + sc] =
            *(const uint4*)(X + (size_t)(row0 + sr) * DM + kt + sc);
        // stage B: 64x64
        *(uint4*)&Bs[sr * 72 + sc] =
            *(const uint4*)(Wbf + (size_t)(col0 + sr) * DM + kt + sc);
        *(uint4*)&Bs[(sr + 32) * 72 + sc] =
            *(const uint4*)(Wbf + (size_t)(col0 + 32 + sr) * DM + kt + sc);
        __syncthreads();

#pragma unroll
        for (int ks = 0; ks < 2; ++ks) {
            bf16x8 af = ld_bf8(&As[(wm + ln15) * 72 + ks * 32 + quad * 8]);
#pragma unroll
            for (int nt = 0; nt < 2; ++nt) {
                bf16x8 bfr = ld_bf8(&Bs[(wn + nt * 16 + ln15) * 72 + ks * 32 + quad * 8]);
                acc[nt] = __builtin_amdgcn_mfma_f32_16x16x32_bf16(af, bfr, acc[nt], 0, 0, 0);
            }
        }
    }

    float bc[2];
#pragma unroll
    for (int nt = 0; nt < 2; ++nt) bc[nt] = bias[col0 + wn + nt * 16 + ln15];
#pragma unroll
    for (int r = 0; r < 4; ++r) {
        int m = row0 + wm + quad * 4 + r;
#pragma unroll
        for (int nt = 0; nt < 2; ++nt)
            out[(size_t)m * DM + col0 + wn + nt * 16 + ln15] = acc[nt][r] + bc[nt];
    }
}

// Combine: C = 64*(sum_z O_z)/(sum_z l_z) -> bf16 into Qb region (Q is dead
// after attn). Memory-bound streaming kernel: grid 1024 x 256, 4 blocks/CU.
__global__ __launch_bounds__(256) void combine(
    const u16* __restrict__ Pd, const float* __restrict__ Cl, u16* __restrict__ C)
{
    int idx = (blockIdx.x * 256 + threadIdx.x) * 8;
    int row = idx >> 9, col = idx & 511;
    int b = row >> 11, s = row & (SEQ - 1), h = col >> 6;
    int bh = b * NUM_H + h;
    float lsum = Cl[bh * SEQ + s] + Cl[32768 + bh * SEQ + s]
               + Cl[65536 + bh * SEQ + s] + Cl[98304 + bh * SEQ + s];
    float sc = 64.f / lsum;
    union { uint4 u; __half2 h2[4]; } u0, u1, u2, u3;
    u0.u = *(const uint4*)&Pd[idx];
    u1.u = *(const uint4*)&Pd[2097152 + idx];
    u2.u = *(const uint4*)&Pd[2 * 2097152 + idx];
    u3.u = *(const uint4*)&Pd[3 * 2097152 + idx];
    float f[8];
#pragma unroll
    for (int j = 0; j < 4; ++j) {
        __half2 s2 = __hadd2(__hadd2(u0.h2[j], u1.h2[j]),
                             __hadd2(u2.h2[j], u3.h2[j]));
        float2 fl = __half22float2(s2);
        f[2 * j]     = fl.x * sc;
        f[2 * j + 1] = fl.y * sc;
    }
    *(uint4*)&C[idx] = pack8bf(f);
}

// ---------------- MFMA flash attention, split-K4, diagonal mask ----------------
// r20 structure (kept): 32x32x16 MFMAs, each wave owns 32 q rows,
// S^T = mfma32(K,Q) so lane holds ONE q (lane&31); l-sum is a scalar
// register; P->PV A-frag via 2 v_permlane32_swap_b32 per 16-k block;
// PV 8 mfma32/tile with b128 V reads. Single-buffer 2-barrier loop + T14
// reg prefetch (r19's 1-barrier dbuf regressed).
#define LSTR 72
// exp(z*0.125 - 4) == exp2(z*0.125*log2e - 4*log2e)
#define SCL2  0.18033688f
#define BIA2 -5.7708020f
__global__ __launch_bounds__(256, 4) void attn_mfma(
    const u16* __restrict__ Qg, const u16* __restrict__ Kg,
    const u16* __restrict__ Vtg, u16* __restrict__ Pd, float* __restrict__ Cl)
{
    __shared__ u16 Klds[64 * LSTR];
    __shared__ u16 Vtlds[64 * LSTR];

    const int tid = threadIdx.x;
    const int lane = tid & 63;
    const int w = tid >> 6;
    const int col = lane & 31;          // q-col / key-row within 32-block
    const int hi  = lane >> 5;
    const int hi8 = hi * 8;
    const int bh = blockIdx.y;
    const int b = bh >> 3, h = bh & 7;
    const int qb = blockIdx.z * 128;    // 16 q-blocks of 128 rows
    const int z = blockIdx.x;           // NZ split-K slabs
    const int k0 = z * (SEQ / NZ), k1 = k0 + SEQ / NZ;

    const u16* Qp = Qg + (size_t)bh * SEQ * DK;
    const u16* Kp = Kg + (size_t)bh * SEQ * DK;
    const u16* Vp = Vtg + (size_t)bh * DK * SEQ;   // [d][s]

    // Q fragments (B-operand): col q = lane&31, dk = dkb*16 + hi8 + j
    const int myq = qb + w * 32 + col;
    bf16x8 qf[4];
#pragma unroll
    for (int dkb = 0; dkb < 4; ++dkb)
        qf[dkb] = ld_bf8(&Qp[(size_t)myq * DK + dkb * 16 + hi8]);

    // diagonal: q == kt + kb32*32 + crow0 + 4*hi, with kt==diag_kt and
    // kb32==(w&1) -> mask reg r where crow0(r) == vtarget.
    const int diag_kt = qb + (w >> 1) * 64;
    const int vtarget = col - 4 * hi;

    f32x16 O0 = {0.f, 0.f, 0.f, 0.f, 0.f, 0.f, 0.f, 0.f,
                 0.f, 0.f, 0.f, 0.f, 0.f, 0.f, 0.f, 0.f};
    f32x16 O1 = O0;
    float lsum = 0.f;

    const int sr = tid >> 3;
    const int scl = (tid & 7) * 8;
    const u16* kp0 = &Kp[(size_t)sr * DK + scl];
    const u16* kp1 = &Kp[(size_t)(sr + 32) * DK + scl];
    const u16* vp0 = &Vp[(size_t)sr * SEQ + scl];
    const u16* vp1 = &Vp[(size_t)(sr + 32) * SEQ + scl];

    // T14 prologue: first tile into regs
    uint4 kreg0 = *(const uint4*)&kp0[(size_t)k0 * DK];
    uint4 kreg1 = *(const uint4*)&kp1[(size_t)k0 * DK];
    uint4 vreg0 = *(const uint4*)&vp0[k0];
    uint4 vreg1 = *(const uint4*)&vp1[k0];

    for (int kt = k0; kt < k1; kt += 64) {
        // write staged regs to LDS (prev compute finished at loop-end barrier)
        *(uint4*)&Klds[sr * LSTR + scl]         = kreg0;
        *(uint4*)&Klds[(sr + 32) * LSTR + scl]  = kreg1;
        *(uint4*)&Vtlds[sr * LSTR + scl]        = vreg0;
        *(uint4*)&Vtlds[(sr + 32) * LSTR + scl] = vreg1;
        __syncthreads();

        // issue next tile's global loads — they complete under compute
        if (kt + 64 < k1) {
            kreg0 = *(const uint4*)&kp0[(size_t)(kt + 64) * DK];
            kreg1 = *(const uint4*)&kp1[(size_t)(kt + 64) * DK];
            vreg0 = *(const uint4*)&vp0[kt + 64];
            vreg1 = *(const uint4*)&vp1[kt + 64];
        }

        const bool diagt = (kt == diag_kt);
        __builtin_amdgcn_s_setprio(1);
#pragma unroll
        for (int kb32 = 0; kb32 < 2; ++kb32) {
            // QK^T: S^T block (32 keys x 32 q)
            f32x16 z16 = {0.f, 0.f, 0.f, 0.f, 0.f, 0.f, 0.f, 0.f,
                          0.f, 0.f, 0.f, 0.f, 0.f, 0.f, 0.f, 0.f};
#pragma unroll
            for (int dkb = 0; dkb < 4; ++dkb) {
                bf16x8 kf = ld_bf8(&Klds[(kb32 * 32 + col) * LSTR + dkb * 16 + hi8]);
                z16 = mfma32(kf, qf[dkb], z16);
            }
            const bool dm = diagt && (kb32 == (w & 1));
#pragma unroll
            for (int c = 0; c < 2; ++c) {       // two 16-k sub-blocks
                float e[8];
#pragma unroll
                for (int i = 0; i < 8; ++i) {
                    const int r = c * 8 + i;
                    float ee = fexp2(fmaf(z16[r], SCL2, BIA2));
                    const int crow0 = (r & 3) + 8 * (r >> 2);
                    if (dm && vtarget == crow0) ee = 0.f;
                    lsum += ee;
                    e[i] = ee;
                }
                u32 a0 = pk2(e[0], e[1]);
                u32 a1 = pk2(e[2], e[3]);
                u32 a2 = pk2(e[4], e[5]);
                u32 a3 = pk2(e[6], e[7]);
                asm("v_permlane32_swap_b32 %0, %1" : "+v"(a0), "+v"(a2));
                asm("v_permlane32_swap_b32 %0, %1" : "+v"(a1), "+v"(a3));
                bf16x8 paf = frag4(a0, a1, a2, a3);
                const int kb16 = kb32 * 2 + c;
                bf16x8 vf0 = ld_bf8(&Vtlds[col * LSTR + kb16 * 16 + hi8]);
                bf16x8 vf1 = ld_bf8(&Vtlds[(32 + col) * LSTR + kb16 * 16 + hi8]);
                O0 = mfma32(paf, vf0, O0);
                O1 = mfma32(paf, vf1, O1);
            }
        }
        __builtin_amdgcn_s_setprio(0);
        __syncthreads();
    }

    // l per q: lane holds q = col; partner lane^32 holds complementary k-set
    float lt = lsum + __shfl_xor(lsum, 32);
    if (lane < 32)
        Cl[(size_t)z * 32768 + bh * SEQ + qb + w * 32 + col] = lt;

    // write unnormalized O partial (fp16, scaled 1/64)
#pragma unroll
    for (int reg = 0; reg < 16; ++reg) {
        const int crow = (reg & 3) + 8 * (reg >> 2) + 4 * hi;
        const int sq = qb + w * 32 + crow;
        size_t base = (size_t)z * 2097152 + ((size_t)(b * SEQ + sq)) * DM + h * DK;
        Pd[base + col]      = f2h(O0[reg] * 0.015625f);
        Pd[base + 32 + col] = f2h(O1[reg] * 0.015625f);
    }
}

extern "C" void kernel_launch(void* const* d_in, const int* in_sizes, int n_in,
                              void* d_out, int out_size, void* d_ws, size_t ws_size,
                              hipStream_t stream) {
    const float* q  = (const float*)d_in[0];
    const float* k  = (const float*)d_in[1];
    const float* v  = (const float*)d_in[2];
    const float* Wq = (const float*)d_in[3];
    const float* bq = (const float*)d_in[4];
    const float* Wk = (const float*)d_in[5];
    const float* bk = (const float*)d_in[6];
    const float* Wv = (const float*)d_in[7];
    const float* bv = (const float*)d_in[8];
    const float* Wo = (const float*)d_in[9];
    const float* bo = (const float*)d_in[10];
    float* out = (float*)d_out;

    // ws layout (~30.5 MB of the 256 MB arena):
    //   Qb, Kb, Vtb   bf16 [4096][512]        4 MB each (Qb reused for C)
    //   Cl            fp32 [NZ][16][2048]     512 KB
    //   Wscr          bf16 Wq,Wk,Wv,Wo        2 MB
    //   Pd            fp16 [NZ][4096][512]    16 MB (attn O-partials)
    const size_t TSZ = (size_t)MROWS * DM;   // 2,097,152
    u16* Qb   = (u16*)d_ws;
    u16* Kb   = Qb + TSZ;
    u16* Vtb  = Qb + 2 * TSZ;
    float* Cl = (float*)(Qb + 3 * TSZ);      // NZ*32768 = 131072 floats
    u16* Wscr = (u16*)(Cl + 131072);         // 4*262144 u16
    u16* Pd   = Wscr + 4 * 262144;           // NZ*TSZ u16

    dim3 blk(256);
    hipLaunchKernelGGL(convW, dim3(128, 4), blk, 0, stream, Wq, Wk, Wv, Wo, Wscr);
    dim3 gq(MROWS / 64, DM / 64, 3);         // (64, 8, 3) = 1536 blocks, 6/CU
    hipLaunchKernelGGL(qkv_mfma, gq, blk, 0, stream,
                       q, k, v, Wscr, bq, bk, bv, Qb, Kb, Vtb);
    dim3 ga(NZ, NB * NUM_H, SEQ / 128);      // (4, 16, 16) = 1024 blocks, 4/CU
    hipLaunchKernelGGL(attn_mfma, ga, blk, 0, stream, Qb, Kb, Vtb, Pd, Cl);
    hipLaunchKernelGGL(combine, dim3(1024), blk, 0, stream, Pd, Cl, Qb);  // C -> Qb
    dim3 gf(MROWS / 32, DM / 64);            // (128, 8) = 1024 blocks, 4/CU
    hipLaunchKernelGGL(final_mfma, gf, blk, 0, stream, Qb, Wscr + 3 * 262144, bo, out);
}

// Round 12
// 146.980 us; speedup vs baseline: 1.0298x; 1.0165x over previous
//
#include <hip/hip_runtime.h>
#include <hip/hip_bf16.h>
#include <hip/hip_fp16.h>
#include <math.h>

#define NUM_H 8
#define DK    64
#define DM    512
#define SEQ   2048
#define NB    2
#define MROWS (NB*SEQ)   // 4096
#define NZ    4          // attn split-K factor

typedef unsigned short u16;
typedef unsigned int   u32;
typedef __attribute__((ext_vector_type(8))) __bf16 bf16x8;
typedef __attribute__((ext_vector_type(4))) short  s16x4;
typedef __attribute__((ext_vector_type(4))) float  f32x4;

// Native RNE cast (compiler emits v_cvt_pk_bf16_f32 for pairs).
__device__ __forceinline__ u16 f2bf(float v) {
    union { __bf16 h; u16 u; } x; x.h = (__bf16)v; return x.u;
}
__device__ __forceinline__ u16 f2h(float v) {
    union { _Float16 h; u16 u; } x; x.h = (_Float16)v; return x.u;
}
__device__ __forceinline__ float h2f(u16 u) {
    union { u16 u; _Float16 h; } x; x.u = u; return (float)x.h;
}
__device__ __forceinline__ bf16x8 ld_bf8(const u16* p) {
    union { uint4 u; bf16x8 v; } t;
    t.u = *(const uint4*)p;
    return t.v;
}
__device__ __forceinline__ uint4 pack8bf(const float* f) {
    uint4 o;
    o.x = (u32)f2bf(f[0]) | ((u32)f2bf(f[1]) << 16);
    o.y = (u32)f2bf(f[2]) | ((u32)f2bf(f[3]) << 16);
    o.z = (u32)f2bf(f[4]) | ((u32)f2bf(f[5]) << 16);
    o.w = (u32)f2bf(f[6]) | ((u32)f2bf(f[7]) << 16);
    return o;
}
// exp2 that maps straight to v_exp_f32 (no hidden *log2e mul).
__device__ __forceinline__ float fexp2(float x) {
#if defined(__has_builtin) && __has_builtin(__builtin_amdgcn_exp2f)
    return __builtin_amdgcn_exp2f(x);
#else
    return exp2f(x);
#endif
}

// K=16 bf16 MFMA (A/B: 4 bf16 in 2 VGPR). Used for PV so the swapped-QK^T
// score layout (lane holds k = nt2*16 + quad*4 + r) feeds MFMA A directly.
__device__ __forceinline__ f32x4 mfma16bf(s16x4 a, s16x4 b, f32x4 c) {
#if defined(__has_builtin) && __has_builtin(__builtin_amdgcn_mfma_f32_16x16x16bf16_1k)
    return __builtin_amdgcn_mfma_f32_16x16x16bf16_1k(a, b, c, 0, 0, 0);
#else
    asm("v_mfma_f32_16x16x16_bf16 %0, %1, %2, %0" : "+v"(c) : "v"(a), "v"(b));
    return c;
#endif
}

// Convert Wq,Wk,Wv,Wo (fp32 512x512) -> bf16 into Wscr. grid (128,4) x 256.
__global__ __launch_bounds__(256) void convW(
    const float* __restrict__ Wq, const float* __restrict__ Wk,
    const float* __restrict__ Wv, const float* __restrict__ Wo,
    u16* __restrict__ Wscr)
{
    const int z = blockIdx.y;
    const float* src = (z == 0) ? Wq : (z == 1) ? Wk : (z == 2) ? Wv : Wo;
    u16* dst = Wscr + (size_t)z * 262144;
    int i = (blockIdx.x * 256 + threadIdx.x) * 8;
    float4 a = *(const float4*)(src + i);
    float4 b = *(const float4*)(src + i + 4);
    float f[8] = {a.x, a.y, a.z, a.w, b.x, b.y, b.z, b.w};
    *(uint4*)&dst[i] = pack8bf(f);
}

// ---------------- MFMA GEMM core: OUT = X @ W^T + bias (W bf16) ----------------
// r21-proven: BM=BN=BK=64, 256 thr / 4 waves (2x2, 32x32 out each), LDS
// stride 72 u16, single-buffer 2-barrier K-loop. No prefetch (r10/r16/r22:
// source-level pipelining regresses; TLP-hidden). Combine de-fused (r21).
#define MODE_QK 0
#define MODE_VT 1
#define MODE_FIN 2

template<int MODE, bool INBF>
__device__ __forceinline__ void gemm_core(
    const void* __restrict__ Xv, const u16* __restrict__ Wb,
    const float* __restrict__ bias, void* __restrict__ outv,
    u16* As, u16* Bs, int row0, int col0)
{
    const int tid = threadIdx.x;
    const int lane = tid & 63, w = tid >> 6;
    const int ln15 = lane & 15, quad = lane >> 4;
    const int wm = (w >> 1) * 32, wn = (w & 1) * 32;

    f32x4 acc[2][2];
#pragma unroll
    for (int mt = 0; mt < 2; ++mt)
#pragma unroll
        for (int nt = 0; nt < 2; ++nt) acc[mt][nt] = (f32x4){0.f, 0.f, 0.f, 0.f};

    for (int kt = 0; kt < DM; kt += 64) {
        __syncthreads();
        // stage A: 64x64
#pragma unroll
        for (int g = 0; g < 2; ++g) {
            int idx = g * 2048 + tid * 8;
            int r = idx >> 6, c = idx & 63;
            if (INBF) {
                *(uint4*)&As[r * 72 + c] =
                    *(const uint4*)((const u16*)Xv + (size_t)(row0 + r) * DM + kt + c);
            } else {
                const float* xp = (const float*)Xv + (size_t)(row0 + r) * DM + kt + c;
                float4 a = *(const float4*)xp;
                float4 b2 = *(const float4*)(xp + 4);
                float f[8] = {a.x, a.y, a.z, a.w, b2.x, b2.y, b2.z, b2.w};
                *(uint4*)&As[r * 72 + c] = pack8bf(f);
            }
        }
        // stage B: 64x64, W bf16 layout [n][k]
#pragma unroll
        for (int g = 0; g < 2; ++g) {
            int idx = g * 2048 + tid * 8;
            int r = idx >> 6, c = idx & 63;
            *(uint4*)&Bs[r * 72 + c] =
                *(const uint4*)(Wb + (size_t)(col0 + r) * DM + kt + c);
        }
        __syncthreads();

#pragma unroll
        for (int ks = 0; ks < 2; ++ks) {
            bf16x8 af[2], bfr[2];
#pragma unroll
            for (int mt = 0; mt < 2; ++mt)
                af[mt] = ld_bf8(&As[(wm + mt * 16 + ln15) * 72 + ks * 32 + quad * 8]);
#pragma unroll
            for (int nt = 0; nt < 2; ++nt)
                bfr[nt] = ld_bf8(&Bs[(wn + nt * 16 + ln15) * 72 + ks * 32 + quad * 8]);
#pragma unroll
            for (int mt = 0; mt < 2; ++mt)
#pragma unroll
                for (int nt = 0; nt < 2; ++nt)
                    acc[mt][nt] = __builtin_amdgcn_mfma_f32_16x16x32_bf16(
                        af[mt], bfr[nt], acc[mt][nt], 0, 0, 0);
        }
    }

    float bc[2];
#pragma unroll
    for (int nt = 0; nt < 2; ++nt) bc[nt] = bias[col0 + wn + nt * 16 + ln15];
    const int h = col0 >> 6;   // BN=64 == one head

    if (MODE == MODE_FIN) {
        float* outF = (float*)outv;
#pragma unroll
        for (int mt = 0; mt < 2; ++mt)
#pragma unroll
            for (int r = 0; r < 4; ++r) {
                int m = row0 + wm + mt * 16 + quad * 4 + r;
#pragma unroll
                for (int nt = 0; nt < 2; ++nt)
                    outF[(size_t)m * DM + col0 + wn + nt * 16 + ln15] = acc[mt][nt][r] + bc[nt];
            }
    } else if (MODE == MODE_QK) {
        u16* outB = (u16*)outv;
#pragma unroll
        for (int mt = 0; mt < 2; ++mt)
#pragma unroll
            for (int r = 0; r < 4; ++r) {
                int m = row0 + wm + mt * 16 + quad * 4 + r;
                int b = m >> 11, s2 = m & (SEQ - 1);
#pragma unroll
                for (int nt = 0; nt < 2; ++nt) {
                    int dk = wn + nt * 16 + ln15;
                    outB[((size_t)((b * NUM_H + h) * SEQ + s2)) * DK + dk] =
                        f2bf(acc[mt][nt][r] + bc[nt]);
                }
            }
    } else {   // MODE_VT: out [b][h][dk][s]; LDS transpose (reuse As, 64x72)
        u16* outB = (u16*)outv;
        __syncthreads();   // all frag reads done before As reuse
#pragma unroll
        for (int mt = 0; mt < 2; ++mt)
#pragma unroll
            for (int nt = 0; nt < 2; ++nt) {
                int dk = wn + nt * 16 + ln15;
#pragma unroll
                for (int r = 0; r < 4; ++r) {
                    int sl = wm + mt * 16 + quad * 4 + r;
                    As[dk * 72 + sl] = f2bf(acc[mt][nt][r] + bc[nt]);
                }
            }
        __syncthreads();
        int dk = tid >> 2, ch = (tid & 3) * 16;
        int b = row0 >> 11, s0 = row0 & (SEQ - 1);
        size_t base = ((size_t)((b * NUM_H + h) * DK + dk)) * SEQ + s0 + ch;
        *(uint4*)&outB[base]     = *(const uint4*)&As[dk * 72 + ch];
        *(uint4*)&outB[base + 8] = *(const uint4*)&As[dk * 72 + ch + 8];
    }
}

// Fused QKV: grid (64, 8, 3). Inputs fp32 (bf16-packed during staging).
__global__ __launch_bounds__(256) void qkv_mfma(
    const float* __restrict__ xq, const float* __restrict__ xk, const float* __restrict__ xv,
    const u16* __restrict__ Wscr,
    const float* __restrict__ b0, const float* __restrict__ b1, const float* __restrict__ b2,
    u16* __restrict__ oQ, u16* __restrict__ oK, u16* __restrict__ oVt)
{
    __shared__ u16 As[64 * 72];
    __shared__ u16 Bs[64 * 72];
    const int row0 = blockIdx.x * 64, col0 = blockIdx.y * 64;
    const int z = blockIdx.z;
    const u16* W = Wscr + (size_t)z * 262144;
    if (z == 2)
        gemm_core<MODE_VT, false>(xv, W, b2, oVt, As, Bs, row0, col0);
    else if (z == 0)
        gemm_core<MODE_QK, false>(xq, W, b0, oQ, As, Bs, row0, col0);
    else
        gemm_core<MODE_QK, false>(xk, W, b1, oK, As, Bs, row0, col0);
}

// Final projection: A is bf16 C from the combine kernel (INBF path). BM=64
// (r23's BM=32 was neutral; keeping the r21-verified shape).
__global__ __launch_bounds__(256) void final_mfma(
    const u16* __restrict__ X, const u16* __restrict__ Wbf,
    const float* __restrict__ bias, float* __restrict__ out)
{
    __shared__ u16 As[64 * 72];
    __shared__ u16 Bs[64 * 72];
    gemm_core<MODE_FIN, true>(X, Wbf, bias, out, As, Bs,
                              blockIdx.x * 64, blockIdx.y * 64);
}

// Combine: C = 64*(sum_z O_z)/(sum_z l_z) -> bf16 into Qb region (Q is dead
// after attn). Memory-bound streaming kernel: grid 1024 x 256, 4 blocks/CU.
__global__ __launch_bounds__(256) void combine(
    const u16* __restrict__ Pd, const float* __restrict__ Cl, u16* __restrict__ C)
{
    int idx = (blockIdx.x * 256 + threadIdx.x) * 8;
    int row = idx >> 9, col = idx & 511;
    int b = row >> 11, s = row & (SEQ - 1), h = col >> 6;
    int bh = b * NUM_H + h;
    float lsum = Cl[bh * SEQ + s] + Cl[32768 + bh * SEQ + s]
               + Cl[65536 + bh * SEQ + s] + Cl[98304 + bh * SEQ + s];
    float sc = 64.f / lsum;
    union { uint4 u; __half2 h2[4]; } u0, u1, u2, u3;
    u0.u = *(const uint4*)&Pd[idx];
    u1.u = *(const uint4*)&Pd[2097152 + idx];
    u2.u = *(const uint4*)&Pd[2 * 2097152 + idx];
    u3.u = *(const uint4*)&Pd[3 * 2097152 + idx];
    float f[8];
#pragma unroll
    for (int j = 0; j < 4; ++j) {
        __half2 s2 = __hadd2(__hadd2(u0.h2[j], u1.h2[j]),
                             __hadd2(u2.h2[j], u3.h2[j]));
        float2 fl = __half22float2(s2);
        f[2 * j]     = fl.x * sc;
        f[2 * j + 1] = fl.y * sc;
    }
    *(uint4*)&C[idx] = pack8bf(f);
}

// ---------------- MFMA flash attention, split-K4, diagonal mask ----------------
// r24: back to the r17-verified 16x16 attn (session-best 146.9us base) —
// r20's 32x32 variant measured ~3us slower on the same fused base (r20 vs
// r17). QBLK=128: each wave owns TWO 16-row q-sets; K/V fragments loaded
// once feed both sets (LDS bytes per work halved). Swapped QK^T (P
// lane-local), T14 reg prefetch, exp2 folded consts, l via ones-MFMA,
// wave-uniform diag guard, setprio around PV. Grid (NZ, bh, qb).
#define LSTR 72
// exp(z*0.125 - 4) == exp2(z*0.125*log2e - 4*log2e)
#define SCL2  0.18033688f
#define BIA2 -5.7708020f
__global__ __launch_bounds__(256, 4) void attn_mfma(
    const u16* __restrict__ Qg, const u16* __restrict__ Kg,
    const u16* __restrict__ Vtg, u16* __restrict__ Pd, float* __restrict__ Cl)
{
    __shared__ u16 Klds[64 * LSTR];
    __shared__ u16 Vtlds[64 * LSTR];

    const int tid = threadIdx.x;
    const int lane = tid & 63;
    const int w = tid >> 6;
    const int ln15 = lane & 15;
    const int quad = lane >> 4;
    const int bh = blockIdx.y;
    const int b = bh >> 3, h = bh & 7;
    const int qb = blockIdx.z * 128;      // 16 q-blocks of 128 rows
    const int z = blockIdx.x;             // NZ split-K slabs
    const int k0 = z * (SEQ / NZ), k1 = k0 + SEQ / NZ;

    const u16* Qp = Qg + (size_t)bh * SEQ * DK;
    const u16* Kp = Kg + (size_t)bh * SEQ * DK;
    const u16* Vp = Vtg + (size_t)bh * DK * SEQ;   // [d][s]

    // two q-sets per wave: q = qb + w*32 + s*16 + ln15
    const int myq0 = w * 32 + ln15;
    bf16x8 qa[2][2];
    qa[0][0] = ld_bf8(&Qp[(size_t)(qb + myq0) * DK + quad * 8]);
    qa[0][1] = ld_bf8(&Qp[(size_t)(qb + myq0) * DK + 32 + quad * 8]);
    qa[1][0] = ld_bf8(&Qp[(size_t)(qb + myq0 + 16) * DK + quad * 8]);
    qa[1][1] = ld_bf8(&Qp[(size_t)(qb + myq0 + 16) * DK + 32 + quad * 8]);

    // diag-mask lane constants: within the wave's diagonal k-tile
    // (kt == qb + (w>>1)*64), set s hits nt2 == (w&1)*2 + s, lane element
    // (quad == ln15>>2, r == ln15&3).
    const bool mrow = (quad == (ln15 >> 2));
    const int  mr   = ln15 & 3;
    const int  diag_kt = qb + (w >> 1) * 64;
    const int  nt2d = (w & 1) * 2;

    const s16x4 onesb = (s16x4){(short)0x3F80, (short)0x3F80,
                                (short)0x3F80, (short)0x3F80};

    f32x4 O[2][4];
    f32x4 Lacc[2];
#pragma unroll
    for (int s = 0; s < 2; ++s) {
        Lacc[s] = (f32x4){0.f, 0.f, 0.f, 0.f};
#pragma unroll
        for (int nt = 0; nt < 4; ++nt) O[s][nt] = (f32x4){0.f, 0.f, 0.f, 0.f};
    }

    const int sr = tid >> 3;
    const int scl = (tid & 7) * 8;
    const u16* kp0 = &Kp[(size_t)sr * DK + scl];
    const u16* kp1 = &Kp[(size_t)(sr + 32) * DK + scl];
    const u16* vp0 = &Vp[(size_t)sr * SEQ + scl];
    const u16* vp1 = &Vp[(size_t)(sr + 32) * SEQ + scl];

    // T14 prologue: first tile into regs
    uint4 kreg0 = *(const uint4*)&kp0[(size_t)k0 * DK];
    uint4 kreg1 = *(const uint4*)&kp1[(size_t)k0 * DK];
    uint4 vreg0 = *(const uint4*)&vp0[k0];
    uint4 vreg1 = *(const uint4*)&vp1[k0];

    for (int kt = k0; kt < k1; kt += 64) {
        // write staged regs to LDS (prev compute finished at loop-end barrier)
        *(uint4*)&Klds[sr * LSTR + scl]         = kreg0;
        *(uint4*)&Klds[(sr + 32) * LSTR + scl]  = kreg1;
        *(uint4*)&Vtlds[sr * LSTR + scl]        = vreg0;
        *(uint4*)&Vtlds[(sr + 32) * LSTR + scl] = vreg1;
        __syncthreads();

        // issue next tile's global loads — they complete under compute
        if (kt + 64 < k1) {
            kreg0 = *(const uint4*)&kp0[(size_t)(kt + 64) * DK];
            kreg1 = *(const uint4*)&kp1[(size_t)(kt + 64) * DK];
            vreg0 = *(const uint4*)&vp0[kt + 64];
            vreg1 = *(const uint4*)&vp1[kt + 64];
        }

        const bool diagt = (kt == diag_kt);
        // swapped QK^T: kb fragments loaded once, feed BOTH q-sets.
        s16x4 pa[2][4];
#pragma unroll
        for (int nt2 = 0; nt2 < 4; ++nt2) {
            bf16x8 kb0 = ld_bf8(&Klds[(nt2 * 16 + ln15) * LSTR + quad * 8]);
            bf16x8 kb1 = ld_bf8(&Klds[(nt2 * 16 + ln15) * LSTR + 32 + quad * 8]);
#pragma unroll
            for (int s = 0; s < 2; ++s) {
                f32x4 zacc = (f32x4){0.f, 0.f, 0.f, 0.f};
                zacc = __builtin_amdgcn_mfma_f32_16x16x32_bf16(kb0, qa[s][0], zacc, 0, 0, 0);
                zacc = __builtin_amdgcn_mfma_f32_16x16x32_bf16(kb1, qa[s][1], zacc, 0, 0, 0);
                union { u16 u[4]; s16x4 v; } pk;
#pragma unroll
                for (int r = 0; r < 4; ++r)
                    pk.u[r] = f2bf(fexp2(fmaf(zacc[r], SCL2, BIA2)));
                if (diagt && nt2 == nt2d + s) {   // wave-uniform guard
#pragma unroll
                    for (int r = 0; r < 4; ++r)
                        if (mrow && r == mr) pk.u[r] = 0;
                }
                pa[s][nt2] = pk.v;
            }
        }

        // PV via K=16 MFMA: vb fragments loaded once, feed BOTH q-sets.
        const u16* vb_base = &Vtlds[ln15 * LSTR + quad * 4];
        __builtin_amdgcn_s_setprio(1);
#pragma unroll
        for (int nt2 = 0; nt2 < 4; ++nt2) {
            Lacc[0] = mfma16bf(pa[0][nt2], onesb, Lacc[0]);
            Lacc[1] = mfma16bf(pa[1][nt2], onesb, Lacc[1]);
        }
#pragma unroll
        for (int nt = 0; nt < 4; ++nt) {
#pragma unroll
            for (int nt2 = 0; nt2 < 4; ++nt2) {
                s16x4 vb = *(const s16x4*)&vb_base[nt * 16 * LSTR + nt2 * 16];
                O[0][nt] = mfma16bf(pa[0][nt2], vb, O[0][nt]);
                O[1][nt] = mfma16bf(pa[1][nt2], vb, O[1][nt]);
            }
        }
        __builtin_amdgcn_s_setprio(0);
        __syncthreads();
    }

    // Lacc[s][r] = l for q = qb + w*32 + s*16 + quad*4 + r (same across ln15)
    if (ln15 == 0) {
#pragma unroll
        for (int s = 0; s < 2; ++s)
#pragma unroll
            for (int r = 0; r < 4; ++r)
                Cl[(size_t)z * 32768 + bh * SEQ + qb + w * 32 + s * 16 + quad * 4 + r]
                    = Lacc[s][r];
    }

    // write unnormalized O partial (fp16, scaled 1/64)
#pragma unroll
    for (int s = 0; s < 2; ++s)
#pragma unroll
        for (int r = 0; r < 4; ++r) {
            int sq = qb + w * 32 + s * 16 + quad * 4 + r;
            size_t base = (size_t)z * 2097152 + ((size_t)(b * SEQ + sq)) * DM + h * DK;
#pragma unroll
            for (int nt = 0; nt < 4; ++nt)
                Pd[base + nt * 16 + ln15] = f2h(O[s][nt][r] * 0.015625f);
        }
}

extern "C" void kernel_launch(void* const* d_in, const int* in_sizes, int n_in,
                              void* d_out, int out_size, void* d_ws, size_t ws_size,
                              hipStream_t stream) {
    const float* q  = (const float*)d_in[0];
    const float* k  = (const float*)d_in[1];
    const float* v  = (const float*)d_in[2];
    const float* Wq = (const float*)d_in[3];
    const float* bq = (const float*)d_in[4];
    const float* Wk = (const float*)d_in[5];
    const float* bk = (const float*)d_in[6];
    const float* Wv = (const float*)d_in[7];
    const float* bv = (const float*)d_in[8];
    const float* Wo = (const float*)d_in[9];
    const float* bo = (const float*)d_in[10];
    float* out = (float*)d_out;

    // ws layout (~30.5 MB of the 256 MB arena):
    //   Qb, Kb, Vtb   bf16 [4096][512]        4 MB each (Qb reused for C)
    //   Cl            fp32 [NZ][16][2048]     512 KB
    //   Wscr          bf16 Wq,Wk,Wv,Wo        2 MB
    //   Pd            fp16 [NZ][4096][512]    16 MB (attn O-partials)
    const size_t TSZ = (size_t)MROWS * DM;   // 2,097,152
    u16* Qb   = (u16*)d_ws;
    u16* Kb   = Qb + TSZ;
    u16* Vtb  = Qb + 2 * TSZ;
    float* Cl = (float*)(Qb + 3 * TSZ);      // NZ*32768 = 131072 floats
    u16* Wscr = (u16*)(Cl + 131072);         // 4*262144 u16
    u16* Pd   = Wscr + 4 * 262144;           // NZ*TSZ u16

    dim3 blk(256);
    hipLaunchKernelGGL(convW, dim3(128, 4), blk, 0, stream, Wq, Wk, Wv, Wo, Wscr);
    dim3 gq(MROWS / 64, DM / 64, 3);         // (64, 8, 3) = 1536 blocks, 6/CU
    hipLaunchKernelGGL(qkv_mfma, gq, blk, 0, stream,
                       q, k, v, Wscr, bq, bk, bv, Qb, Kb, Vtb);
    dim3 ga(NZ, NB * NUM_H, SEQ / 128);      // (4, 16, 16) = 1024 blocks, 4/CU
    hipLaunchKernelGGL(attn_mfma, ga, blk, 0, stream, Qb, Kb, Vtb, Pd, Cl);
    hipLaunchKernelGGL(combine, dim3(1024), blk, 0, stream, Pd, Cl, Qb);  // C -> Qb
    dim3 gf(MROWS / 64, DM / 64);            // (64, 8) = 512 blocks, 2/CU
    hipLaunchKernelGGL(final_mfma, gf, blk, 0, stream, Qb, Wscr + 3 * 262144, bo, out);
}